// Round 15
// baseline (1757.870 us; speedup 1.0000x reference)
//
#include <hip/hip_runtime.h>

// VectorQuantizer: B=32768, K=8192, D=256, fp32.
// out layout (flat float): z_q [B*D], vq_loss [1], commit [1], indices-as-float [B]
// ws layout: idx_i int[B] | s_z float[B] | partial float[B/4]
//
// Numerics (verified round 2): ref dist = fl32(S - 2*fl32(dot)), dot = single
// fp32 FMA chain ascending in d per (row,code); frequent exact ties resolved
// by FIRST index. fmaf(-2,acc,S) == fl(S - 2*dot) exactly.
//
// Measured laws (r2-r14):
//  - VGPR cap 128 @512thr (acc>64 spills), comfort ~152 @256thr.
//  - LDS: 96KB single block allocates (r8/r14); 2x64KB does NOT co-reside.
//  - Stage model (r14): per CU per stage VALU 2048 cyc, LDS ~2320 cyc
//    (eb dense 1540 + za bcast 400 + writes 384) -> LDS co-binding at rows=8;
//    rows=16 needs ~190 VGPR (impossible). Stall ~800-1000 cyc per BARRIER
//    ITERATION, topology-independent; fat stages amortize it (r14: the only
//    win since r9).
//
// Round-15: BK=16, BN=256 (same per-stage FMA volume & LDS economics as r14,
// HALF the barrier iterations: 512 vs 1024). LDS = zT 64KB + eT[2][16][256]
// 32KB = 96KB (proven size). codes/thread=4 -> acc=32, VGPR ~80 (no spill,
// scheduler headroom). 512 thr, 8 waves, 8 rows/wave.

namespace {
constexpr int NB = 32768;
constexpr int NK = 8192;
constexpr int ND = 256;
constexpr int BM = 64;    // rows per block (8 waves x 8 rows)
constexpr int BN = 256;   // codes per chunk
constexpr int BK = 16;    // d per stage
constexpr int NT = 512;   // threads per block (8 waves)

// ---- S[row] = ||z_row||^2 ----
__global__ void sz_kernel(const float* __restrict__ z, float* __restrict__ sz) {
  const int row = blockIdx.x * 4 + (threadIdx.x >> 6);
  const int lane = threadIdx.x & 63;
  const float4 v = reinterpret_cast<const float4*>(z)[(size_t)row * (ND / 4) + lane];
  float s = v.x * v.x + v.y * v.y + v.z * v.z + v.w * v.w;
#pragma unroll
  for (int off = 32; off; off >>= 1) s += __shfl_down(s, off, 64);
  if (lane == 0) sz[row] = s;
}

// ---- argmin over codes of fl32(S - 2*fl32(z.e)), first-index tie-break ----
__global__ __launch_bounds__(NT, 1) void argmin_kernel(
    const float* __restrict__ z, const float* __restrict__ emb,
    const float* __restrict__ sz, int* __restrict__ idx_i,
    float* __restrict__ idx_f) {
  __shared__ float zT[ND][BM];       // 64 KB, persistent z^T tile
  __shared__ float eT[2][BK][BN];    // 32 KB, double-buffered e^T stage

  const int tid = threadIdx.x;
  const int tx = tid & 63;   // code lane (full wave)
  const int ty = tid >> 6;   // wave id = row group (0..7), wave-uniform
  const int ty8 = ty * 8;
  const int row0 = blockIdx.x * BM;

  // stage zT (transpose z[row][d] -> zT[d][row]); coalesced, one-time
  {
    const float4* z4 = reinterpret_cast<const float4*>(z) + (size_t)row0 * 64;
#pragma unroll
    for (int it = 0; it < 8; ++it) {
      int fi = it * NT + tid;  // float4 index in tile (64 rows * 64 f4/row)
      int r = fi >> 6;
      int dq = fi & 63;
      float4 v = z4[(size_t)r * 64 + dq];
      zT[dq * 4 + 0][r] = v.x;
      zT[dq * 4 + 1][r] = v.y;
      zT[dq * 4 + 2][r] = v.z;
      zT[dq * 4 + 3][r] = v.w;
    }
  }
  // first zT read happens after the first in-loop __syncthreads()

  float best[8];
  int bidx[8];
#pragma unroll
  for (int i = 0; i < 8; ++i) { best[i] = 3.4e38f; bidx[i] = 0; }

  const float4* e4 = reinterpret_cast<const float4*>(emb);
  const int cstage = tid & 255;   // staged code (2 threads per code)
  const int hstage = tid >> 8;    // d-octet within the 16-d stage (0 or 1)

  float eb[2][4];
  auto leb = [&](int b, int buf, int dd) {
    const float4 e0 = *reinterpret_cast<const float4*>(&eT[buf][dd][tx * 4]);
    eb[b][0] = e0.x; eb[b][1] = e0.y; eb[b][2] = e0.z; eb[b][3] = e0.w;
  };

  for (int n = 0; n < NK / BN; ++n) {  // 32 chunks
    const int c0 = n * BN;
    float acc[8][4];
#pragma unroll
    for (int i = 0; i < 8; ++i)
#pragma unroll
      for (int j = 0; j < 4; ++j) acc[i][j] = 0.f;

    // thread stages code c0+cstage, d-octet hstage: 2 float4 per stage
    const float4* ecode = e4 + (size_t)(c0 + cstage) * 64;
    float4 p0 = ecode[hstage * 2];
    float4 p1 = ecode[hstage * 2 + 1];

    for (int dk = 0; dk < ND / BK; ++dk) {  // 16 fat stages
      const int buf = dk & 1;
      const int h8 = hstage * 8;
      // transposed store eT[dd][code]; 256 consecutive lanes per dd row
      eT[buf][h8 + 0][cstage] = p0.x;
      eT[buf][h8 + 1][cstage] = p0.y;
      eT[buf][h8 + 2][cstage] = p0.z;
      eT[buf][h8 + 3][cstage] = p0.w;
      eT[buf][h8 + 4][cstage] = p1.x;
      eT[buf][h8 + 5][cstage] = p1.y;
      eT[buf][h8 + 6][cstage] = p1.z;
      eT[buf][h8 + 7][cstage] = p1.w;
      if (dk + 1 < ND / BK) {  // prefetch next stage (~4000-cyc window)
        p0 = ecode[(dk + 1) * 4 + hstage * 2];
        p1 = ecode[(dk + 1) * 4 + hstage * 2 + 1];
      }
      __syncthreads();  // dbuf: single barrier per stage
      leb(0, buf, 0);
#pragma unroll
      for (int dd = 0; dd < BK; ++dd) {
        const int cur = dd & 1;
        if (dd < BK - 1) leb(cur ^ 1, buf, dd + 1);  // prefetch next dd's eb
        const int d = dk * BK + dd;
        // za: one address per wave (ty uniform) -> free broadcast b128 reads
        const float4 a0 = *reinterpret_cast<const float4*>(&zT[d][ty8]);
        const float4 a1 = *reinterpret_cast<const float4*>(&zT[d][ty8 + 4]);
        const float za[8] = {a0.x, a0.y, a0.z, a0.w, a1.x, a1.y, a1.z, a1.w};
        // single fp32 FMA chain per (row, code), ascending d
#pragma unroll
        for (int i = 0; i < 8; ++i)
#pragma unroll
          for (int j = 0; j < 4; ++j)
            acc[i][j] = fmaf(za[i], eb[cur][j], acc[i][j]);
      }
    }

    // running argmin: dist = fl32(S - 2*fl32(dot)); ascending code order
#pragma unroll
    for (int i = 0; i < 8; ++i) {
      const float S = sz[row0 + ty8 + i];  // wave-uniform, cache-hot
#pragma unroll
      for (int s = 0; s < 4; ++s) {
        const float dist = fmaf(-2.0f, acc[i][s], S);
        const int code = c0 + tx * 4 + s;
        if (dist < best[i]) {  // strict <: earliest index wins
          best[i] = dist;
          bidx[i] = code;
        }
      }
    }
  }

  // full-wave (64 lane) reduce; prefer smaller index on exact ties
#pragma unroll
  for (int i = 0; i < 8; ++i) {
    float bv = best[i];
    int bi = bidx[i];
#pragma unroll
    for (int m = 1; m < 64; m <<= 1) {
      float ov = __shfl_xor(bv, m, 64);
      int oi = __shfl_xor(bi, m, 64);
      if (ov < bv || (ov == bv && oi < bi)) { bv = ov; bi = oi; }
    }
    if (tx == 0) {
      int row = row0 + ty8 + i;
      idx_i[row] = bi;
      idx_f[row] = (float)bi;
    }
  }
}

// ---- gather z_q = emb[idx], partial sums of (z_q - z)^2 ----
__global__ void gather_kernel(const float* __restrict__ z,
                              const float* __restrict__ emb,
                              const int* __restrict__ idx,
                              float* __restrict__ zq,
                              float* __restrict__ partial) {
  const int w = threadIdx.x >> 6;
  const int lane = threadIdx.x & 63;
  const int row = blockIdx.x * 4 + w;
  const int k = idx[row];
  const float4 e = reinterpret_cast<const float4*>(emb)[(size_t)k * (ND / 4) + lane];
  const float4 zv = reinterpret_cast<const float4*>(z)[(size_t)row * (ND / 4) + lane];
  reinterpret_cast<float4*>(zq)[(size_t)row * (ND / 4) + lane] = e;
  const float dx = e.x - zv.x, dy = e.y - zv.y, dz = e.z - zv.z, dw = e.w - zv.w;
  float s = dx * dx + dy * dy + dz * dz + dw * dw;
#pragma unroll
  for (int off = 32; off; off >>= 1) s += __shfl_down(s, off, 64);
  __shared__ float sm[4];
  if (lane == 0) sm[w] = s;
  __syncthreads();
  if (threadIdx.x == 0) partial[blockIdx.x] = sm[0] + sm[1] + sm[2] + sm[3];
}

// ---- deterministic final loss reduction ----
__global__ void loss_kernel(const float* __restrict__ partial, int n,
                            float* __restrict__ out_loss) {
  double s = 0.0;
  for (int i = threadIdx.x; i < n; i += 256) s += (double)partial[i];
  __shared__ double sm[256];
  sm[threadIdx.x] = s;
  __syncthreads();
  for (int st = 128; st; st >>= 1) {
    if (threadIdx.x < st) sm[threadIdx.x] += sm[threadIdx.x + st];
    __syncthreads();
  }
  if (threadIdx.x == 0) {
    float loss = (float)(0.25 * sm[0] / (double)((size_t)NB * ND));
    out_loss[0] = loss;  // vq_loss
    out_loss[1] = loss;  // commitment loss (same forward value)
  }
}

}  // namespace

extern "C" void kernel_launch(void* const* d_in, const int* in_sizes, int n_in,
                              void* d_out, int out_size, void* d_ws, size_t ws_size,
                              hipStream_t stream) {
  const float* z = (const float*)d_in[0];
  const float* emb = (const float*)d_in[1];
  float* out = (float*)d_out;
  float* zq = out;
  float* loss = out + (size_t)NB * ND;
  float* idx_f = out + (size_t)NB * ND + 2;

  int* idx_i = (int*)d_ws;
  float* sz = (float*)((char*)d_ws + (size_t)NB * 4);
  float* partial = (float*)((char*)d_ws + (size_t)NB * 4 * 2);

  sz_kernel<<<NB / 4, 256, 0, stream>>>(z, sz);
  argmin_kernel<<<NB / BM, NT, 0, stream>>>(z, emb, sz, idx_i, idx_f);
  gather_kernel<<<NB / 4, 256, 0, stream>>>(z, emb, idx_i, zq, partial);
  loss_kernel<<<1, 256, 0, stream>>>(partial, NB / 4, loss);
}

// Round 16
// 1603.579 us; speedup vs baseline: 1.0962x; 1.0962x over previous
//
#include <hip/hip_runtime.h>

// VectorQuantizer: B=32768, K=8192, D=256, fp32.
// out layout (flat float): z_q [B*D], vq_loss [1], commit [1], indices-as-float [B]
// ws layout: idx_i int[B] | s_z float[B] | partial float[B/4]
//
// Numerics (verified round 2): ref dist = fl32(S - 2*fl32(dot)), dot = single
// fp32 FMA chain ascending in d per (row,code); frequent exact ties resolved
// by FIRST index. fmaf(-2,acc,S) == fl(S - 2*dot) exactly.
//
// Measured laws (r2-r15):
//  - VGPR cap 128 @512thr; pegging it -> scratch spill (r14: 5MB @ VGPR=128).
//  - LDS: 96KB single block OK; 128KB (any split) does NOT fit the pool.
//  - Iterations = 2*(NK*ND)/(BN*BK); stall ~1200-1500cyc per iteration,
//    topology-independent. r14 (BN*BK=4096, 1024 iters) is the max fat-stage
//    config under the LDS pool: next halving needs eT 64KB -> 128KB total. 
//  - r15 lesson: BKxBN reshuffle at constant product = same iters, more za
//    traffic -> regression. za reads scale with BK at fixed eb reuse.
//
// Round-16 = r14 de-pressurized:
//   identical geometry (512thr/8 waves, BM=64, BN=512, BK=8, tile 8x8,
//   zT 64KB + eT[2][8][512] 32KB = 96KB, 1024 fat iterations);
//   - NO manual eb dbuf (full dd unroll -> compiler schedules 32 ds_reads +
//     512 FMAs with the freed register headroom; ~10 VGPR saved, spill gone)
//   - induction-pointer LDS addressing (bases advance once per stage; reads
//     at compile-time offsets -> ds_read offset immediates, less VALU).

namespace {
constexpr int NB = 32768;
constexpr int NK = 8192;
constexpr int ND = 256;
constexpr int BM = 64;    // rows per block (8 waves x 8 rows)
constexpr int BN = 512;   // codes per chunk
constexpr int BK = 8;     // d per stage
constexpr int NT = 512;   // threads per block (8 waves)

// ---- S[row] = ||z_row||^2 ----
__global__ void sz_kernel(const float* __restrict__ z, float* __restrict__ sz) {
  const int row = blockIdx.x * 4 + (threadIdx.x >> 6);
  const int lane = threadIdx.x & 63;
  const float4 v = reinterpret_cast<const float4*>(z)[(size_t)row * (ND / 4) + lane];
  float s = v.x * v.x + v.y * v.y + v.z * v.z + v.w * v.w;
#pragma unroll
  for (int off = 32; off; off >>= 1) s += __shfl_down(s, off, 64);
  if (lane == 0) sz[row] = s;
}

// ---- argmin over codes of fl32(S - 2*fl32(z.e)), first-index tie-break ----
__global__ __launch_bounds__(NT, 1) void argmin_kernel(
    const float* __restrict__ z, const float* __restrict__ emb,
    const float* __restrict__ sz, int* __restrict__ idx_i,
    float* __restrict__ idx_f) {
  __shared__ float zT[ND][BM];       // 64 KB, persistent z^T tile
  __shared__ float eT[2][BK][BN];    // 32 KB, double-buffered e^T stage

  const int tid = threadIdx.x;
  const int tx = tid & 63;   // code lane (full wave)
  const int ty = tid >> 6;   // wave id = row group (0..7), wave-uniform
  const int ty8 = ty * 8;
  const int row0 = blockIdx.x * BM;

  // stage zT (transpose z[row][d] -> zT[d][row]); coalesced, one-time
  {
    const float4* z4 = reinterpret_cast<const float4*>(z) + (size_t)row0 * 64;
#pragma unroll
    for (int it = 0; it < 8; ++it) {
      int fi = it * NT + tid;  // float4 index in tile (64 rows * 64 f4/row)
      int r = fi >> 6;
      int dq = fi & 63;
      float4 v = z4[(size_t)r * 64 + dq];
      zT[dq * 4 + 0][r] = v.x;
      zT[dq * 4 + 1][r] = v.y;
      zT[dq * 4 + 2][r] = v.z;
      zT[dq * 4 + 3][r] = v.w;
    }
  }
  // first zT read happens after the first in-loop __syncthreads()

  float best[8];
  int bidx[8];
#pragma unroll
  for (int i = 0; i < 8; ++i) { best[i] = 3.4e38f; bidx[i] = 0; }

  const float4* e4 = reinterpret_cast<const float4*>(emb);

  // fixed per-thread LDS base pointers (offsets become ds_read immediates)
  const float* zbase0 = &zT[0][ty8];            // + d*BM
  const float* ebase0 = &eT[0][0][tx * 4];      // + buf*BK*BN + dd*BN (+256)

  for (int n = 0; n < NK / BN; ++n) {  // 16 chunks
    const int c0 = n * BN;
    float acc[8][8];
#pragma unroll
    for (int i = 0; i < 8; ++i)
#pragma unroll
      for (int j = 0; j < 8; ++j) acc[i][j] = 0.f;

    // thread owns code row c0+tid; stage 8 d per iter = 2 float4
    const float4* ecode = e4 + (size_t)(c0 + tid) * 64;
    float4 p0 = ecode[0];
    float4 p1 = ecode[1];

    const float* zrow = zbase0;  // advances BK*BM floats per stage

    for (int dk = 0; dk < ND / BK; ++dk) {  // 32 fat stages
      const int buf = dk & 1;
      // transposed store eT[dd][code]; all 512 lanes consecutive per dd
      {
        float* ew = &eT[buf][0][tid];
        ew[0 * BN] = p0.x;
        ew[1 * BN] = p0.y;
        ew[2 * BN] = p0.z;
        ew[3 * BN] = p0.w;
        ew[4 * BN] = p1.x;
        ew[5 * BN] = p1.y;
        ew[6 * BN] = p1.z;
        ew[7 * BN] = p1.w;
      }
      if (dk + 1 < ND / BK) {  // prefetch next stage (~2000-cyc window)
        p0 = ecode[(dk + 1) * 2];
        p1 = ecode[(dk + 1) * 2 + 1];
      }
      __syncthreads();  // dbuf: single barrier per stage
      const float* er = ebase0 + buf * (BK * BN);
#pragma unroll
      for (int dd = 0; dd < BK; ++dd) {
        // eb: 2 dense b128 at constant offsets from er
        const float4 e0 = *reinterpret_cast<const float4*>(er + dd * BN);
        const float4 e1 = *reinterpret_cast<const float4*>(er + dd * BN + 256);
        const float eb[8] = {e0.x, e0.y, e0.z, e0.w, e1.x, e1.y, e1.z, e1.w};
        // za: wave-uniform broadcast b128 at constant offsets from zrow
        const float4 a0 = *reinterpret_cast<const float4*>(zrow + dd * BM);
        const float4 a1 = *reinterpret_cast<const float4*>(zrow + dd * BM + 4);
        const float za[8] = {a0.x, a0.y, a0.z, a0.w, a1.x, a1.y, a1.z, a1.w};
        // single fp32 FMA chain per (row, code), ascending d
#pragma unroll
        for (int i = 0; i < 8; ++i)
#pragma unroll
          for (int j = 0; j < 8; ++j)
            acc[i][j] = fmaf(za[i], eb[j], acc[i][j]);
      }
      zrow += BK * BM;
    }

    // running argmin: dist = fl32(S - 2*fl32(dot)); ascending code order
#pragma unroll
    for (int i = 0; i < 8; ++i) {
      const float S = sz[row0 + ty8 + i];  // wave-uniform, cache-hot
#pragma unroll
      for (int m = 0; m < 2; ++m)
#pragma unroll
        for (int s = 0; s < 4; ++s) {
          const float dist = fmaf(-2.0f, acc[i][m * 4 + s], S);
          const int code = c0 + m * 256 + tx * 4 + s;
          if (dist < best[i]) {  // strict <: earliest index wins
            best[i] = dist;
            bidx[i] = code;
          }
        }
    }
  }

  // full-wave (64 lane) reduce; prefer smaller index on exact ties
#pragma unroll
  for (int i = 0; i < 8; ++i) {
    float bv = best[i];
    int bi = bidx[i];
#pragma unroll
    for (int m = 1; m < 64; m <<= 1) {
      float ov = __shfl_xor(bv, m, 64);
      int oi = __shfl_xor(bi, m, 64);
      if (ov < bv || (ov == bv && oi < bi)) { bv = ov; bi = oi; }
    }
    if (tx == 0) {
      int row = row0 + ty8 + i;
      idx_i[row] = bi;
      idx_f[row] = (float)bi;
    }
  }
}

// ---- gather z_q = emb[idx], partial sums of (z_q - z)^2 ----
__global__ void gather_kernel(const float* __restrict__ z,
                              const float* __restrict__ emb,
                              const int* __restrict__ idx,
                              float* __restrict__ zq,
                              float* __restrict__ partial) {
  const int w = threadIdx.x >> 6;
  const int lane = threadIdx.x & 63;
  const int row = blockIdx.x * 4 + w;
  const int k = idx[row];
  const float4 e = reinterpret_cast<const float4*>(emb)[(size_t)k * (ND / 4) + lane];
  const float4 zv = reinterpret_cast<const float4*>(z)[(size_t)row * (ND / 4) + lane];
  reinterpret_cast<float4*>(zq)[(size_t)row * (ND / 4) + lane] = e;
  const float dx = e.x - zv.x, dy = e.y - zv.y, dz = e.z - zv.z, dw = e.w - zv.w;
  float s = dx * dx + dy * dy + dz * dz + dw * dw;
#pragma unroll
  for (int off = 32; off; off >>= 1) s += __shfl_down(s, off, 64);
  __shared__ float sm[4];
  if (lane == 0) sm[w] = s;
  __syncthreads();
  if (threadIdx.x == 0) partial[blockIdx.x] = sm[0] + sm[1] + sm[2] + sm[3];
}

// ---- deterministic final loss reduction ----
__global__ void loss_kernel(const float* __restrict__ partial, int n,
                            float* __restrict__ out_loss) {
  double s = 0.0;
  for (int i = threadIdx.x; i < n; i += 256) s += (double)partial[i];
  __shared__ double sm[256];
  sm[threadIdx.x] = s;
  __syncthreads();
  for (int st = 128; st; st >>= 1) {
    if (threadIdx.x < st) sm[threadIdx.x] += sm[threadIdx.x + st];
    __syncthreads();
  }
  if (threadIdx.x == 0) {
    float loss = (float)(0.25 * sm[0] / (double)((size_t)NB * ND));
    out_loss[0] = loss;  // vq_loss
    out_loss[1] = loss;  // commitment loss (same forward value)
  }
}

}  // namespace

extern "C" void kernel_launch(void* const* d_in, const int* in_sizes, int n_in,
                              void* d_out, int out_size, void* d_ws, size_t ws_size,
                              hipStream_t stream) {
  const float* z = (const float*)d_in[0];
  const float* emb = (const float*)d_in[1];
  float* out = (float*)d_out;
  float* zq = out;
  float* loss = out + (size_t)NB * ND;
  float* idx_f = out + (size_t)NB * ND + 2;

  int* idx_i = (int*)d_ws;
  float* sz = (float*)((char*)d_ws + (size_t)NB * 4);
  float* partial = (float*)((char*)d_ws + (size_t)NB * 4 * 2);

  sz_kernel<<<NB / 4, 256, 0, stream>>>(z, sz);
  argmin_kernel<<<NB / BM, NT, 0, stream>>>(z, emb, sz, idx_i, idx_f);
  gather_kernel<<<NB / 4, 256, 0, stream>>>(z, emb, idx_i, zq, partial);
  loss_kernel<<<1, 256, 0, stream>>>(partial, NB / 4, loss);
}

// Round 17
// 1582.539 us; speedup vs baseline: 1.1108x; 1.0133x over previous
//
#include <hip/hip_runtime.h>

// VectorQuantizer: B=32768, K=8192, D=256, fp32.
// out layout (flat float): z_q [B*D], vq_loss [1], commit [1], indices-as-float [B]
// ws layout: idx_i int[B] | s_z float[B] | partial float[B/4]
//
// Numerics (verified round 2): ref dist = fl32(S - 2*fl32(dot)), dot = single
// fp32 FMA chain ascending in d per (row,code); frequent exact ties resolved
// by FIRST index. fmaf(-2,acc,S) == fl(S - 2*dot) exactly.
//
// Measured laws (r2-r16):
//  - VGPR cap 128 @512thr; LDS pool ~96-127KB; iterations=2*(NK*ND)/(BN*BK);
//  - barrier-stage wall ~4380cyc: VALU 2890 + LDS 2900 co-busy, stall ~1450
//    = store->barrier->load convoy of 8 lockstep waves. Fat stages maxed.
//
// Round-17: BARRIER-FREE main loop. Wave w owns codes [c0+w*64, +64) per
// chunk, staged into wave-PRIVATE eT[w][8][64] (single-buffered: same-wave
// DS ops are hardware-ordered; no cross-wave consumer). Lane (rg,cg) =
// rows rg*8..+8 x codes cg*8..+8. Same 512 FMA/stage/lane, same stage count,
// ZERO __syncthreads in the K-loop. za: 8-distinct-addr b128 (2-way, cheap).
// Final: shfl over cg, then cross-wave combine via 4KB LDS (ascending wave,
// lower-index-on-tie => exact np.argmin semantics).

namespace {
constexpr int NB = 32768;
constexpr int NK = 8192;
constexpr int ND = 256;
constexpr int BM = 64;    // rows per block
constexpr int NT = 512;   // threads per block (8 waves)

// ---- S[row] = ||z_row||^2 ----
__global__ void sz_kernel(const float* __restrict__ z, float* __restrict__ sz) {
  const int row = blockIdx.x * 4 + (threadIdx.x >> 6);
  const int lane = threadIdx.x & 63;
  const float4 v = reinterpret_cast<const float4*>(z)[(size_t)row * (ND / 4) + lane];
  float s = v.x * v.x + v.y * v.y + v.z * v.z + v.w * v.w;
#pragma unroll
  for (int off = 32; off; off >>= 1) s += __shfl_down(s, off, 64);
  if (lane == 0) sz[row] = s;
}

// ---- argmin over codes of fl32(S - 2*fl32(z.e)), first-index tie-break ----
__global__ __launch_bounds__(NT, 1) void argmin_kernel(
    const float* __restrict__ z, const float* __restrict__ emb,
    const float* __restrict__ sz, int* __restrict__ idx_i,
    float* __restrict__ idx_f) {
  __shared__ float zT[ND][BM];      // 64 KB, persistent z^T tile (read-only)
  __shared__ float eT[8][8][64];    // 16 KB, wave-private e slices
  __shared__ float cbv[8][BM];      // 2 KB, cross-wave combine (values)
  __shared__ int cbi[8][BM];        // 2 KB, cross-wave combine (indices)

  const int tid = threadIdx.x;
  const int lane = tid & 63;
  const int w = tid >> 6;       // wave id: owns codes c0 + w*64 .. +64
  const int rg = lane >> 3;     // row group: rows rg*8 .. +8
  const int cg = lane & 7;      // code group: wave-local codes cg*8 .. +8
  const int row0 = blockIdx.x * BM;

  // stage zT (transpose z[row][d] -> zT[d][row]); coalesced, one-time
  {
    const float4* z4 = reinterpret_cast<const float4*>(z) + (size_t)row0 * 64;
#pragma unroll
    for (int it = 0; it < 8; ++it) {
      int fi = it * NT + tid;  // float4 index in tile (64 rows * 64 f4/row)
      int r = fi >> 6;
      int dq = fi & 63;
      float4 v = z4[(size_t)r * 64 + dq];
      zT[dq * 4 + 0][r] = v.x;
      zT[dq * 4 + 1][r] = v.y;
      zT[dq * 4 + 2][r] = v.z;
      zT[dq * 4 + 3][r] = v.w;
    }
  }
  __syncthreads();  // the ONLY pre-loop barrier; zT is read-only afterwards

  float best[8];
  int bidx[8];
#pragma unroll
  for (int i = 0; i < 8; ++i) { best[i] = 3.4e38f; bidx[i] = 0; }

  const float4* e4 = reinterpret_cast<const float4*>(emb);

  for (int n = 0; n < NK / 512; ++n) {  // 16 chunks of 512 codes
    const int c0 = n * 512;
    const int mycode = c0 + w * 64 + lane;  // code this lane stages
    float acc[8][8];
#pragma unroll
    for (int i = 0; i < 8; ++i)
#pragma unroll
      for (int j = 0; j < 8; ++j) acc[i][j] = 0.f;

    const float4* ecode = e4 + (size_t)mycode * 64;
    float4 p0 = ecode[0];
    float4 p1 = ecode[1];

    const float* zrow = &zT[0][rg * 8];   // advances 8*BM floats per stage
    const float* er = &eT[w][0][cg * 8];  // wave-private, fixed
    float* ew = &eT[w][0][lane];          // wave-private, fixed

    for (int dk = 0; dk < 32; ++dk) {  // 32 barrier-FREE stages (8 d each)
      // stage this wave's 64 codes x 8 d (same-wave DS ordering => safe,
      // single-buffered; no other wave ever touches eT[w])
      ew[0 * 64] = p0.x;
      ew[1 * 64] = p0.y;
      ew[2 * 64] = p0.z;
      ew[3 * 64] = p0.w;
      ew[4 * 64] = p1.x;
      ew[5 * 64] = p1.y;
      ew[6 * 64] = p1.z;
      ew[7 * 64] = p1.w;
      if (dk + 1 < 32) {  // prefetch next stage (hidden under 512 FMAs)
        p0 = ecode[(dk + 1) * 2];
        p1 = ecode[(dk + 1) * 2 + 1];
      }
#pragma unroll
      for (int dd = 0; dd < 8; ++dd) {
        // eb: 2 b128, 8 distinct addrs/wave (2-way bank alias = cheap)
        const float4 e0 = *reinterpret_cast<const float4*>(er + dd * 64);
        const float4 e1 = *reinterpret_cast<const float4*>(er + dd * 64 + 4);
        const float eb[8] = {e0.x, e0.y, e0.z, e0.w, e1.x, e1.y, e1.z, e1.w};
        // za: 2 b128, 8 distinct addrs/wave (broadcast within row-group)
        const float4 a0 = *reinterpret_cast<const float4*>(zrow + dd * BM);
        const float4 a1 = *reinterpret_cast<const float4*>(zrow + dd * BM + 4);
        const float za[8] = {a0.x, a0.y, a0.z, a0.w, a1.x, a1.y, a1.z, a1.w};
        // single fp32 FMA chain per (row, code), ascending d
#pragma unroll
        for (int i = 0; i < 8; ++i)
#pragma unroll
          for (int j = 0; j < 8; ++j)
            acc[i][j] = fmaf(za[i], eb[j], acc[i][j]);
      }
      zrow += 8 * BM;
    }

    // running argmin: dist = fl32(S - 2*fl32(dot)); ascending code order
#pragma unroll
    for (int i = 0; i < 8; ++i) {
      const float S = sz[row0 + rg * 8 + i];  // cache-hot
#pragma unroll
      for (int j = 0; j < 8; ++j) {
        const float dist = fmaf(-2.0f, acc[i][j], S);
        const int code = c0 + w * 64 + cg * 8 + j;
        if (dist < best[i]) {  // strict <: earliest index wins
          best[i] = dist;
          bidx[i] = code;
        }
      }
    }
  }

  // reduce across the 8 cg lanes of each row group (prefer smaller index)
#pragma unroll
  for (int i = 0; i < 8; ++i) {
    float bv = best[i];
    int bi = bidx[i];
#pragma unroll
    for (int m = 1; m < 8; m <<= 1) {
      float ov = __shfl_xor(bv, m, 64);
      int oi = __shfl_xor(bi, m, 64);
      if (ov < bv || (ov == bv && oi < bi)) { bv = ov; bi = oi; }
    }
    if (cg == 0) {
      cbv[w][rg * 8 + i] = bv;
      cbi[w][rg * 8 + i] = bi;
    }
  }
  __syncthreads();

  // cross-wave combine: ascending wave scan, lower index wins exact ties
  if (tid < BM) {
    float bv = 3.4e38f;
    int bi = 0;
#pragma unroll
    for (int ww = 0; ww < 8; ++ww) {
      const float ov = cbv[ww][tid];
      const int oi = cbi[ww][tid];
      if (ov < bv || (ov == bv && oi < bi)) { bv = ov; bi = oi; }
    }
    idx_i[row0 + tid] = bi;
    idx_f[row0 + tid] = (float)bi;
  }
}

// ---- gather z_q = emb[idx], partial sums of (z_q - z)^2 ----
__global__ void gather_kernel(const float* __restrict__ z,
                              const float* __restrict__ emb,
                              const int* __restrict__ idx,
                              float* __restrict__ zq,
                              float* __restrict__ partial) {
  const int w = threadIdx.x >> 6;
  const int lane = threadIdx.x & 63;
  const int row = blockIdx.x * 4 + w;
  const int k = idx[row];
  const float4 e = reinterpret_cast<const float4*>(emb)[(size_t)k * (ND / 4) + lane];
  const float4 zv = reinterpret_cast<const float4*>(z)[(size_t)row * (ND / 4) + lane];
  reinterpret_cast<float4*>(zq)[(size_t)row * (ND / 4) + lane] = e;
  const float dx = e.x - zv.x, dy = e.y - zv.y, dz = e.z - zv.z, dw = e.w - zv.w;
  float s = dx * dx + dy * dy + dz * dz + dw * dw;
#pragma unroll
  for (int off = 32; off; off >>= 1) s += __shfl_down(s, off, 64);
  __shared__ float sm[4];
  if (lane == 0) sm[w] = s;
  __syncthreads();
  if (threadIdx.x == 0) partial[blockIdx.x] = sm[0] + sm[1] + sm[2] + sm[3];
}

// ---- deterministic final loss reduction ----
__global__ void loss_kernel(const float* __restrict__ partial, int n,
                            float* __restrict__ out_loss) {
  double s = 0.0;
  for (int i = threadIdx.x; i < n; i += 256) s += (double)partial[i];
  __shared__ double sm[256];
  sm[threadIdx.x] = s;
  __syncthreads();
  for (int st = 128; st; st >>= 1) {
    if (threadIdx.x < st) sm[threadIdx.x] += sm[threadIdx.x + st];
    __syncthreads();
  }
  if (threadIdx.x == 0) {
    float loss = (float)(0.25 * sm[0] / (double)((size_t)NB * ND));
    out_loss[0] = loss;  // vq_loss
    out_loss[1] = loss;  // commitment loss (same forward value)
  }
}

}  // namespace

extern "C" void kernel_launch(void* const* d_in, const int* in_sizes, int n_in,
                              void* d_out, int out_size, void* d_ws, size_t ws_size,
                              hipStream_t stream) {
  const float* z = (const float*)d_in[0];
  const float* emb = (const float*)d_in[1];
  float* out = (float*)d_out;
  float* zq = out;
  float* loss = out + (size_t)NB * ND;
  float* idx_f = out + (size_t)NB * ND + 2;

  int* idx_i = (int*)d_ws;
  float* sz = (float*)((char*)d_ws + (size_t)NB * 4);
  float* partial = (float*)((char*)d_ws + (size_t)NB * 4 * 2);

  sz_kernel<<<NB / 4, 256, 0, stream>>>(z, sz);
  argmin_kernel<<<NB / BM, NT, 0, stream>>>(z, emb, sz, idx_i, idx_f);
  gather_kernel<<<NB / 4, 256, 0, stream>>>(z, emb, idx_i, zq, partial);
  loss_kernel<<<1, 256, 0, stream>>>(partial, NB / 4, loss);
}

// Round 18
// 1561.623 us; speedup vs baseline: 1.1257x; 1.0134x over previous
//
#include <hip/hip_runtime.h>

// VectorQuantizer: B=32768, K=8192, D=256, fp32.
// out layout (flat float): z_q [B*D], vq_loss [1], commit [1], indices-as-float [B]
// ws layout: s_z float[B] | partial float[B/BM]
//
// Numerics (verified round 2): ref dist = fl32(S - 2*fl32(dot)), dot = single
// fp32 FMA chain ascending in d per (row,code); frequent exact ties resolved
// by FIRST index. fmaf(-2,acc,S) == fl(S - 2*dot) exactly.
//
// Measured laws (r2-r17):
//  - VGPR cap 128 @512thr; LDS pool ~96-127KB; granule ~32KB.
//  - Barrier-stage convoy ~1450cyc/stage removed by wave-private slices (r17):
//    wave w stages codes [c0+w*64,+64) into private eT[w] (same-wave DS
//    ordering => single-buffered, zero main-loop __syncthreads).
//  - Remaining: ~25% dual-wave LDS-latency stall + ~980cyc/stage fixed VALU
//    overhead; both structure-invariant across r14/r16/r17.
//
// Round-18 = r17 + gather/loss fusion (gather_kernel deleted; zq + loss
// partials produced in the argmin epilogue) + Srow register hoist + guarded
// pointer-bump prefetch.

namespace {
constexpr int NB = 32768;
constexpr int NK = 8192;
constexpr int ND = 256;
constexpr int BM = 64;    // rows per block
constexpr int NT = 512;   // threads per block (8 waves)

// ---- S[row] = ||z_row||^2 ----
__global__ void sz_kernel(const float* __restrict__ z, float* __restrict__ sz) {
  const int row = blockIdx.x * 4 + (threadIdx.x >> 6);
  const int lane = threadIdx.x & 63;
  const float4 v = reinterpret_cast<const float4*>(z)[(size_t)row * (ND / 4) + lane];
  float s = v.x * v.x + v.y * v.y + v.z * v.z + v.w * v.w;
#pragma unroll
  for (int off = 32; off; off >>= 1) s += __shfl_down(s, off, 64);
  if (lane == 0) sz[row] = s;
}

// ---- argmin + fused gather/zq/loss-partial ----
__global__ __launch_bounds__(NT, 1) void argmin_kernel(
    const float* __restrict__ z, const float* __restrict__ emb,
    const float* __restrict__ sz, float* __restrict__ idx_f,
    float* __restrict__ zq, float* __restrict__ partial) {
  __shared__ float zT[ND][BM];      // 64 KB, persistent z^T tile (read-only)
  __shared__ float eT[8][8][64];    // 16 KB, wave-private e slices
  __shared__ float cbv[8][BM];      // 2 KB, cross-wave combine (values)
  __shared__ int cbi[8][BM];        // 2 KB, cross-wave combine (indices)
  __shared__ int kfin[BM];          // final code per row
  __shared__ float wsums[8];        // per-wave loss partials

  const int tid = threadIdx.x;
  const int lane = tid & 63;
  const int w = tid >> 6;       // wave id: owns codes c0 + w*64 .. +64
  const int rg = lane >> 3;     // row group: rows rg*8 .. +8
  const int cg = lane & 7;      // code group: wave-local codes cg*8 .. +8
  const int row0 = blockIdx.x * BM;

  // stage zT (transpose z[row][d] -> zT[d][row]); coalesced, one-time
  {
    const float4* z4 = reinterpret_cast<const float4*>(z) + (size_t)row0 * 64;
#pragma unroll
    for (int it = 0; it < 8; ++it) {
      int fi = it * NT + tid;  // float4 index in tile (64 rows * 64 f4/row)
      int r = fi >> 6;
      int dq = fi & 63;
      float4 v = z4[(size_t)r * 64 + dq];
      zT[dq * 4 + 0][r] = v.x;
      zT[dq * 4 + 1][r] = v.y;
      zT[dq * 4 + 2][r] = v.z;
      zT[dq * 4 + 3][r] = v.w;
    }
  }
  __syncthreads();  // zT read-only afterwards; main loop is barrier-free

  float Srow[8];
#pragma unroll
  for (int i = 0; i < 8; ++i) Srow[i] = sz[row0 + rg * 8 + i];

  float best[8];
  int bidx[8];
#pragma unroll
  for (int i = 0; i < 8; ++i) { best[i] = 3.4e38f; bidx[i] = 0; }

  const float4* e4 = reinterpret_cast<const float4*>(emb);

  for (int n = 0; n < NK / 512; ++n) {  // 16 chunks of 512 codes
    const int c0 = n * 512;
    const int mycode = c0 + w * 64 + lane;  // code this lane stages
    float acc[8][8];
#pragma unroll
    for (int i = 0; i < 8; ++i)
#pragma unroll
      for (int j = 0; j < 8; ++j) acc[i][j] = 0.f;

    const float4* ecode = e4 + (size_t)mycode * 64;
    float4 p0 = ecode[0];
    float4 p1 = ecode[1];
    ecode += 2;

    const float* zrow = &zT[0][rg * 8];   // advances 8*BM floats per stage
    const float* er = &eT[w][0][cg * 8];  // wave-private, fixed
    float* ew = &eT[w][0][lane];          // wave-private, fixed

    for (int dk = 0; dk < 32; ++dk) {  // 32 barrier-FREE stages (8 d each)
      // stage this wave's 64 codes x 8 d (same-wave DS ordering => safe)
      ew[0 * 64] = p0.x;
      ew[1 * 64] = p0.y;
      ew[2 * 64] = p0.z;
      ew[3 * 64] = p0.w;
      ew[4 * 64] = p1.x;
      ew[5 * 64] = p1.y;
      ew[6 * 64] = p1.z;
      ew[7 * 64] = p1.w;
      if (dk + 1 < 32) {  // guarded pointer-bump prefetch
        p0 = ecode[0];
        p1 = ecode[1];
        ecode += 2;
      }
#pragma unroll
      for (int dd = 0; dd < 8; ++dd) {
        const float4 e0 = *reinterpret_cast<const float4*>(er + dd * 64);
        const float4 e1 = *reinterpret_cast<const float4*>(er + dd * 64 + 4);
        const float eb[8] = {e0.x, e0.y, e0.z, e0.w, e1.x, e1.y, e1.z, e1.w};
        const float4 a0 = *reinterpret_cast<const float4*>(zrow + dd * BM);
        const float4 a1 = *reinterpret_cast<const float4*>(zrow + dd * BM + 4);
        const float za[8] = {a0.x, a0.y, a0.z, a0.w, a1.x, a1.y, a1.z, a1.w};
        // single fp32 FMA chain per (row, code), ascending d
#pragma unroll
        for (int i = 0; i < 8; ++i)
#pragma unroll
          for (int j = 0; j < 8; ++j)
            acc[i][j] = fmaf(za[i], eb[j], acc[i][j]);
      }
      zrow += 8 * BM;
    }

    // running argmin: dist = fl32(S - 2*fl32(dot)); ascending code order
#pragma unroll
    for (int i = 0; i < 8; ++i) {
#pragma unroll
      for (int j = 0; j < 8; ++j) {
        const float dist = fmaf(-2.0f, acc[i][j], Srow[i]);
        const int code = c0 + w * 64 + cg * 8 + j;
        if (dist < best[i]) {  // strict <: earliest index wins
          best[i] = dist;
          bidx[i] = code;
        }
      }
    }
  }

  // reduce across the 8 cg lanes of each row group (prefer smaller index)
#pragma unroll
  for (int i = 0; i < 8; ++i) {
    float bv = best[i];
    int bi = bidx[i];
#pragma unroll
    for (int m = 1; m < 8; m <<= 1) {
      float ov = __shfl_xor(bv, m, 64);
      int oi = __shfl_xor(bi, m, 64);
      if (ov < bv || (ov == bv && oi < bi)) { bv = ov; bi = oi; }
    }
    if (cg == 0) {
      cbv[w][rg * 8 + i] = bv;
      cbi[w][rg * 8 + i] = bi;
    }
  }
  __syncthreads();

  // cross-wave combine: ascending wave scan, lower index wins exact ties
  if (tid < BM) {
    float bv = 3.4e38f;
    int bi = 0;
#pragma unroll
    for (int ww = 0; ww < 8; ++ww) {
      const float ov = cbv[ww][tid];
      const int oi = cbi[ww][tid];
      if (ov < bv || (ov == bv && oi < bi)) { bv = ov; bi = oi; }
    }
    idx_f[row0 + tid] = (float)bi;
    kfin[tid] = bi;
  }
  __syncthreads();

  // fused gather: wave w handles rows w*8 .. +8; coalesced float4 per row
  {
    const float4* z4 = reinterpret_cast<const float4*>(z);
    float4* zq4 = reinterpret_cast<float4*>(zq);
    float s = 0.f;
#pragma unroll
    for (int rr = 0; rr < 8; ++rr) {
      const int row = w * 8 + rr;
      const int k = kfin[row];
      const float4 e = e4[(size_t)k * 64 + lane];
      const float4 zv = z4[(size_t)(row0 + row) * 64 + lane];
      zq4[(size_t)(row0 + row) * 64 + lane] = e;
      const float dx = e.x - zv.x, dy = e.y - zv.y;
      const float dz = e.z - zv.z, dw = e.w - zv.w;
      s += dx * dx + dy * dy + dz * dz + dw * dw;
    }
#pragma unroll
    for (int off = 32; off; off >>= 1) s += __shfl_down(s, off, 64);
    if (lane == 0) wsums[w] = s;
  }
  __syncthreads();
  if (tid == 0) {
    float t = 0.f;
#pragma unroll
    for (int ww = 0; ww < 8; ++ww) t += wsums[ww];
    partial[blockIdx.x] = t;
  }
}

// ---- deterministic final loss reduction ----
__global__ void loss_kernel(const float* __restrict__ partial, int n,
                            float* __restrict__ out_loss) {
  double s = 0.0;
  for (int i = threadIdx.x; i < n; i += 256) s += (double)partial[i];
  __shared__ double sm[256];
  sm[threadIdx.x] = s;
  __syncthreads();
  for (int st = 128; st; st >>= 1) {
    if (threadIdx.x < st) sm[threadIdx.x] += sm[threadIdx.x + st];
    __syncthreads();
  }
  if (threadIdx.x == 0) {
    float loss = (float)(0.25 * sm[0] / (double)((size_t)NB * ND));
    out_loss[0] = loss;  // vq_loss
    out_loss[1] = loss;  // commitment loss (same forward value)
  }
}

}  // namespace

extern "C" void kernel_launch(void* const* d_in, const int* in_sizes, int n_in,
                              void* d_out, int out_size, void* d_ws, size_t ws_size,
                              hipStream_t stream) {
  const float* z = (const float*)d_in[0];
  const float* emb = (const float*)d_in[1];
  float* out = (float*)d_out;
  float* zq = out;
  float* loss = out + (size_t)NB * ND;
  float* idx_f = out + (size_t)NB * ND + 2;

  float* sz = (float*)d_ws;
  float* partial = (float*)((char*)d_ws + (size_t)NB * 4);

  sz_kernel<<<NB / 4, 256, 0, stream>>>(z, sz);
  argmin_kernel<<<NB / BM, NT, 0, stream>>>(z, emb, sz, idx_f, zq, partial);
  loss_kernel<<<1, 256, 0, stream>>>(partial, NB / BM, loss);
}